// Round 2
// baseline (586.053 us; speedup 1.0000x reference)
//
#include <hip/hip_runtime.h>
#include <hip/hip_fp16.h>

typedef __attribute__((ext_vector_type(8))) _Float16 half8;
typedef __attribute__((ext_vector_type(4))) float f32x4;

#define B_TOT 8192
#define HDIM  128
#define NDEEP 5
#define PDIM  196
#define QDIM  49
#define BM    16

__device__ __forceinline__ float tanh_fast(float v) {
    // tanh(v) = 1 - 2/(e^{2v}+1); saturates correctly at +-inf
    float e = __expf(v + v);
    return 1.0f - __fdividef(2.0f, e + 1.0f);
}

__device__ __forceinline__ float fquant(float v, float mn, float sc) {
    // 8-bit uniform fake-quant: IEEE f32 div + rint (half-even) to match numpy
    return rintf((v - mn) / sc) * sc + mn;
}

// Single fused kernel: in-kernel weight quantization (no workspace), pix GEMM,
// 49-step scan with 5 register-resident-weight MFMA layers, FC head.
// grid=512 blocks x 256 threads (4 waves). Block owns 16 batch rows.
// Wave w owns output cols [w*32, w*32+32) = two 16-col MFMA tiles.
__global__ __launch_bounds__(256) void dfr_all(
    const float* __restrict__ x,    const float* __restrict__ cell_out,
    const float* __restrict__ W0,   const float* __restrict__ a0p,
    const float* __restrict__ Wd,   const float* __restrict__ adp,
    const float* __restrict__ p1W,  const float* __restrict__ p1b,
    const float* __restrict__ fc1W, const float* __restrict__ fc2W,
    const float* __restrict__ fc2b, float* __restrict__ out)
{
    __shared__ __align__(16) char smem[40000];
    float* pix  = (float*)smem;        // [16][49] f32 (3136 B); sred[8] early; tmp[16][8] late
    char*  bufb = smem + 3136;         // [2][16 rows][256 B] f16 activations, XOR-swizzled (8192 B)
    char*  regC = smem + 11328;        // phase0: pq f16 [64][224] (28672 B); epilogue: hs4 f32 [16][132]

    const int tid  = threadIdx.x;
    const int lane = tid & 63;
    const int w    = tid >> 6;         // wave 0..3
    const int l15  = lane & 15;
    const int l4   = lane >> 4;
    const int r0   = blockIdx.x * BM;

    float* sred = (float*)smem;        // 8-float reduce scratch (dead before pix is written)

    // ---- per-tensor min/max (block-redundant; all inputs L2/L3-resident) ----
    float qmn[8], qsc[8];              // 0:p1W 1:W0 2:fc1W 3..7:Wd[0..4]  (static indexing only)
    {
        const float* srcs[8] = { p1W, W0, fc1W, Wd, Wd + HDIM*HDIM, Wd + 2*HDIM*HDIM,
                                 Wd + 3*HDIM*HDIM, Wd + 4*HDIM*HDIM };
        const int    ns[8]   = { QDIM*PDIM, HDIM, 8*HDIM, HDIM*HDIM, HDIM*HDIM,
                                 HDIM*HDIM, HDIM*HDIM, HDIM*HDIM };
#pragma unroll
        for (int s = 0; s < 8; s++) {
            const float* p = srcs[s]; const int n = ns[s];
            float mn = 1e30f, mx = -1e30f;
            for (int i = tid; i < n; i += 256) { float v = p[i]; mn = fminf(mn, v); mx = fmaxf(mx, v); }
            for (int off = 32; off; off >>= 1) {
                mn = fminf(mn, __shfl_down(mn, off));
                mx = fmaxf(mx, __shfl_down(mx, off));
            }
            if (lane == 0) { sred[w] = mn; sred[4 + w] = mx; }
            __syncthreads();
            mn = fminf(fminf(sred[0], sred[1]), fminf(sred[2], sred[3]));
            mx = fmaxf(fmaxf(sred[4], sred[5]), fmaxf(sred[6], sred[7]));
            __syncthreads();
            qmn[s] = mn; qsc[s] = (mx - mn) / 255.0f;
        }
    }

    // ---- persistent deep weights -> quantized f16 B-fragments in registers ----
    half8 bw[NDEEP][2][4];             // 40 x half8 = 160 VGPR
#pragma unroll
    for (int i = 0; i < NDEEP; i++) {
        const float mn = qmn[3 + i], sc = qsc[3 + i];
#pragma unroll
        for (int nt = 0; nt < 2; nt++)
#pragma unroll
            for (int kc = 0; kc < 4; kc++) {
                const float* src = Wd + (size_t)i * HDIM * HDIM
                                 + (size_t)(w * 32 + nt * 16 + l15) * HDIM + kc * 32 + l4 * 8;
                half8 h;
#pragma unroll
                for (int j = 0; j < 8; j++) h[j] = (_Float16)fquant(src[j], mn, sc);
                bw[i][nt][kc] = h;
            }
    }

    const float a0 = a0p[0];
    float adv[NDEEP];
#pragma unroll
    for (int i = 0; i < NDEEP; i++) adv[i] = adp[i];

    // h0 elementwise path: thread owns row hr, 8 cols hc0..hc0+7
    const int hr  = tid >> 4;          // 0..15
    const int hc0 = (tid & 15) * 8;
    float w0v[8], h0v[8];
#pragma unroll
    for (int j = 0; j < 8; j++) {
        w0v[j] = fquant(W0[hc0 + j], qmn[1], qsc[1]);
        h0v[j] = cell_out[(size_t)(r0 + hr) * HDIM + hc0 + j];
    }

    // deep recurrent state in MFMA C layout: row = l4*4+j, col = w*32 + nt*16 + l15
    const int crow  = l4 * 4;
    const int ccol0 = w * 32 + l15;
    f32x4 st[NDEEP][2];
#pragma unroll
    for (int i = 0; i < NDEEP; i++)
#pragma unroll
        for (int nt = 0; nt < 2; nt++)
#pragma unroll
            for (int j = 0; j < 4; j++)
                st[i][nt][j] = cell_out[(size_t)(1 + i) * B_TOT * HDIM
                                 + (size_t)(r0 + crow + j) * HDIM + ccol0 + nt * 16];

    // ---------------- phase 0: pix = quant(x) @ qweight(p1_W)^T + p1_b ----------------
    _Float16* xq = (_Float16*)bufb;    // [16][224], K zero-padded
    _Float16* pq = (_Float16*)regC;    // [64][224], rows>=49 and cols>=196 zeroed
    for (int idx = tid; idx < 16 * 224; idx += 256) {
        int r = idx / 224, p = idx - r * 224;
        float v = 0.0f;
        if (p < PDIM) {
            v = x[(size_t)(r0 + r) * PDIM + p];
            v = fminf(fmaxf(v, -0.45f), 3.55f);
            const float sc = 4.0f / 255.0f;    // (3.55 - (-0.45)) rounds to exactly 4.0f
            v = rintf((v + 0.45f) / sc) * sc - 0.45f;
        }
        xq[idx] = (_Float16)v;
    }
    {
        const float mn = qmn[0], sc = qsc[0];
        for (int idx = tid; idx < 64 * 224; idx += 256) {
            int q = idx / 224, p = idx - q * 224;
            float v = 0.0f;
            if (q < QDIM && p < PDIM) v = fquant(p1W[q * PDIM + p], mn, sc);
            pq[idx] = (_Float16)v;
        }
    }
    __syncthreads();
    {
        f32x4 accp = {0.f, 0.f, 0.f, 0.f};
#pragma unroll
        for (int kc = 0; kc < 7; kc++) {
            half8 a = *(const half8*)(xq + l15 * 224 + kc * 32 + l4 * 8);
            half8 b = *(const half8*)(pq + (w * 16 + l15) * 224 + kc * 32 + l4 * 8);
            accp = __builtin_amdgcn_mfma_f32_16x16x32_f16(a, b, accp, 0, 0, 0);
        }
        int col = w * 16 + l15;
        if (col < QDIM) {
            float bias = p1b[col];
#pragma unroll
            for (int j = 0; j < 4; j++)
                pix[(l4 * 4 + j) * QDIM + col] = accp[j] + bias;
        }
    }
    __syncthreads();

    // ---------------- main scan: 49 x (h0 elementwise + 5 MFMA layers) ----------------
    const int arow = l15;
    const int aswz = (arow & 7) << 4;                  // LDS XOR swizzle (G4)
    const float*   pixrow = pix + hr * QDIM;
    const uint32_t h0off  = (uint32_t)(hr * 256 + (((tid & 15) * 16) ^ ((hr & 7) << 4)));

#pragma unroll 1
    for (int t = 0; t < QDIM; t++) {
        float px = pixrow[t];
        half8 hh;
#pragma unroll
        for (int j = 0; j < 8; j++) {
            float v = tanh_fast(px * w0v[j] + a0 * h0v[j]);   // fp32 state carry
            h0v[j] = v;
            hh[j]  = (_Float16)v;
        }
        *(half8*)(bufb + h0off) = hh;                  // full 16x128 tile overwrite (buffer 0)
        __syncthreads();

        int rb = 0;
#pragma unroll
        for (int i = 0; i < NDEEP; i++) {
            f32x4 acc0 = st[i][0] * adv[i];            // C init = ad[i] * hs_old (fp32)
            f32x4 acc1 = st[i][1] * adv[i];
            const char* rbase = bufb + rb * 4096;
#pragma unroll
            for (int kc = 0; kc < 4; kc++) {
                half8 a = *(const half8*)(rbase + arow * 256 + ((kc * 64 + l4 * 16) ^ aswz));
                acc0 = __builtin_amdgcn_mfma_f32_16x16x32_f16(a, bw[i][0][kc], acc0, 0, 0, 0);
                acc1 = __builtin_amdgcn_mfma_f32_16x16x32_f16(a, bw[i][1][kc], acc1, 0, 0, 0);
            }
#pragma unroll
            for (int j = 0; j < 4; j++) {
                acc0[j] = tanh_fast(acc0[j]);
                acc1[j] = tanh_fast(acc1[j]);
            }
            st[i][0] = acc0;
            st[i][1] = acc1;
            if (i < NDEEP - 1) {                       // last layer output never re-read via LDS
                char* wb = bufb + (rb ^ 1) * 4096;
#pragma unroll
                for (int j = 0; j < 4; j++) {
                    int row = crow + j;
                    int sw  = (row & 7) << 4;
                    *(_Float16*)(wb + row * 256 + ((ccol0 * 2) ^ sw))      = (_Float16)acc0[j];
                    *(_Float16*)(wb + row * 256 + ((ccol0 * 2 + 32) ^ sw)) = (_Float16)acc1[j];
                }
            }
            __syncthreads();
            rb ^= 1;
        }
    }

    // ---------------- epilogue: out = relu(hs4 @ qweight(fc1)^T) @ fc2^T + fc2b ----------------
    float* hs4 = (float*)regC;                         // [16][132] (pad kills bank conflicts)
#pragma unroll
    for (int nt = 0; nt < 2; nt++)
#pragma unroll
        for (int j = 0; j < 4; j++)
            hs4[(crow + j) * 132 + ccol0 + nt * 16] = st[NDEEP - 1][nt][j];
    __syncthreads();

    float* tmp = pix;                                  // [16][8]
    if (tid < 128) {
        int r = tid >> 3, jj = tid & 7;
        const float* hrow = hs4 + r * 132;
        const float* fw   = fc1W + jj * HDIM;
        const float mn = qmn[2], sc = qsc[2];
        float acc = 0.f;
#pragma unroll 4
        for (int p = 0; p < HDIM; p++) acc += hrow[p] * fquant(fw[p], mn, sc);
        tmp[r * 8 + jj] = fmaxf(acc, 0.f);
    }
    __syncthreads();
    if (tid < 160) {
        int r = tid / 10, o = tid - r * 10;
        float acc = fc2b[o];
#pragma unroll
        for (int jj = 0; jj < 8; jj++) acc += tmp[r * 8 + jj] * fc2W[o * 8 + jj];
        out[(size_t)(r0 + r) * 10 + o] = acc;
    }
}

extern "C" void kernel_launch(void* const* d_in, const int* in_sizes, int n_in,
                              void* d_out, int out_size, void* d_ws, size_t ws_size,
                              hipStream_t stream)
{
    const float* x    = (const float*)d_in[0];
    const float* cell = (const float*)d_in[1];
    const float* W0   = (const float*)d_in[2];
    const float* a0   = (const float*)d_in[3];
    const float* Wd   = (const float*)d_in[4];
    const float* ad   = (const float*)d_in[5];
    const float* p1W  = (const float*)d_in[6];
    const float* p1b  = (const float*)d_in[7];
    const float* fc1  = (const float*)d_in[8];
    const float* fc2W = (const float*)d_in[9];
    const float* fc2b = (const float*)d_in[10];

    dfr_all<<<512, 256, 0, stream>>>(x, cell, W0, a0, Wd, ad, p1W, p1b,
                                     fc1, fc2W, fc2b, (float*)d_out);
}

// Round 4
// 361.276 us; speedup vs baseline: 1.6222x; 1.6222x over previous
//
#include <hip/hip_runtime.h>
#include <hip/hip_fp16.h>

typedef __attribute__((ext_vector_type(8))) _Float16 half8;
typedef __attribute__((ext_vector_type(4))) _Float16 half4;
typedef __attribute__((ext_vector_type(4))) float f32x4;

#define B_TOT 8192
#define HDIM  128
#define NDEEP 5
#define PDIM  196
#define QDIM  49
#define BM    16
#define NPHASE (QDIM + NDEEP)   // 54, even

__device__ __forceinline__ float tanh_fast(float v) {
    // tanh(v) = 1 - 2/(exp(2v)+1); exp(2v) = exp2(v * 2*log2(e)). Saturates at +-inf.
    float e = __builtin_amdgcn_exp2f(v * 2.885390082f);
    float r = __builtin_amdgcn_rcpf(e + 1.0f);
    return fmaf(-2.0f, r, 1.0f);
}

__device__ __forceinline__ float fquant(float v, float mn, float sc) {
    // 8-bit uniform fake-quant: IEEE f32 div + rint (half-even) to match numpy
    return rintf((v - mn) / sc) * sc + mn;
}

// Fully fused DFR. grid=512 x 256 thr (4 waves). Block owns 16 batch rows.
// Swapped MFMA operands: A = weights (out-neuron in l15 of A-frag), B = activations
// (batch in l15), D: col=batch, row=out-neuron -> per-thread 4 consecutive neurons
// for one batch => contiguous 8B LDS writes.
// Diagonal pipeline: phase p runs h0(t=p) and deep layer i at t=p-1-i concurrently;
// ONE barrier per phase (54 total vs 294).
__global__ __launch_bounds__(256, 2) void dfr_all(
    const float* __restrict__ x,    const float* __restrict__ cell_out,
    const float* __restrict__ W0,   const float* __restrict__ a0p,
    const float* __restrict__ Wd,   const float* __restrict__ adp,
    const float* __restrict__ p1W,  const float* __restrict__ p1b,
    const float* __restrict__ fc1W, const float* __restrict__ fc2W,
    const float* __restrict__ fc2b, float* __restrict__ out)
{
    __shared__ __align__(16) char smem[4096 + 10 * 4096];
    float* pix  = (float*)smem;          // [16 batch][64] f32 (q cols 0..48 valid)
    char*  actp = smem + 4096;           // act[producer 0..4][slot 0..1]: 16 rows x 256 B, XOR-swizzled

    const int tid  = threadIdx.x;
    const int lane = tid & 63;
    const int w    = tid >> 6;           // wave 0..3 (owns out-neuron cols w*32..w*32+31)
    const int l15  = lane & 15;
    const int l4   = lane >> 4;
    const int r0   = blockIdx.x * BM;

    float* sred = (float*)smem;          // reduce scratch (dead before pix written)

    // ---- per-tensor min/max (block-redundant, L2-resident) ----
    float qmn[8], qsc[8];                // 0:p1W 1:W0 2:fc1W 3..7:Wd[0..4]
    {
        const float* srcs[8] = { p1W, W0, fc1W, Wd, Wd + HDIM*HDIM, Wd + 2*HDIM*HDIM,
                                 Wd + 3*HDIM*HDIM, Wd + 4*HDIM*HDIM };
        const int    ns[8]   = { QDIM*PDIM, HDIM, 8*HDIM, HDIM*HDIM, HDIM*HDIM,
                                 HDIM*HDIM, HDIM*HDIM, HDIM*HDIM };
#pragma unroll
        for (int s = 0; s < 8; s++) {
            const float* p = srcs[s]; const int n = ns[s];
            float mn = 1e30f, mx = -1e30f;
            for (int i = tid; i < n; i += 256) { float v = p[i]; mn = fminf(mn, v); mx = fmaxf(mx, v); }
            for (int off = 32; off; off >>= 1) {
                mn = fminf(mn, __shfl_down(mn, off));
                mx = fmaxf(mx, __shfl_down(mx, off));
            }
            if (lane == 0) { sred[w] = mn; sred[4 + w] = mx; }
            __syncthreads();
            mn = fminf(fminf(sred[0], sred[1]), fminf(sred[2], sred[3]));
            mx = fmaxf(fmaxf(sred[4], sred[5]), fmaxf(sred[6], sred[7]));
            __syncthreads();
            qmn[s] = mn; qsc[s] = (mx - mn) / 255.0f;
        }
    }

    // ---- deep weights -> quantized f16 A-fragments in registers ----
    half8 bw[NDEEP][2][4];               // [layer][ntile][kc] : 160 VGPR
#pragma unroll
    for (int i = 0; i < NDEEP; i++) {
        const float mn = qmn[3 + i], sc = qsc[3 + i];
#pragma unroll
        for (int nt = 0; nt < 2; nt++)
#pragma unroll
            for (int kc = 0; kc < 4; kc++) {
                const float* src = Wd + (size_t)i * HDIM * HDIM
                                 + (size_t)(w * 32 + nt * 16 + l15) * HDIM + kc * 32 + l4 * 8;
                half8 h;
#pragma unroll
                for (int j = 0; j < 8; j++) h[j] = (_Float16)fquant(src[j], mn, sc);
                bw[i][nt][kc] = h;
            }
    }

    const float a0 = a0p[0];
    float adv[NDEEP];
#pragma unroll
    for (int i = 0; i < NDEEP; i++) adv[i] = adp[i];

    // h0 elementwise: thread owns batch hr, 8 neurons hc0..hc0+7
    const int hr  = tid >> 4;
    const int hc0 = (tid & 15) * 8;
    float w0v[8], h0v[8];
#pragma unroll
    for (int j = 0; j < 8; j++) {
        w0v[j] = fquant(W0[hc0 + j], qmn[1], qsc[1]);
        h0v[j] = cell_out[(size_t)(r0 + hr) * HDIM + hc0 + j];
    }

    // deep state, D layout: col(batch)=l15, row(neuron within tile)=l4*4+j, tiles (w,nt)
    f32x4 st[NDEEP][2];
#pragma unroll
    for (int i = 0; i < NDEEP; i++)
#pragma unroll
        for (int nt = 0; nt < 2; nt++)
            st[i][nt] = *(const f32x4*)(cell_out + (size_t)(1 + i) * B_TOT * HDIM
                                 + (size_t)(r0 + l15) * HDIM + w * 32 + nt * 16 + l4 * 4);

    // ---------------- phase 0: pix = quant(x) @ qweight(p1_W)^T + p1_b ----------------
    {
        _Float16* pq = (_Float16*)actp;            // [64][224]  (q rows, zero-padded)
        _Float16* xq = (_Float16*)(actp + 28672);  // [16][224]  (batch rows, zero-padded)
        for (int idx = tid; idx < 16 * 224; idx += 256) {
            int r = idx / 224, p = idx - r * 224;
            float v = 0.0f;
            if (p < PDIM) {
                v = x[(size_t)(r0 + r) * PDIM + p];
                v = fminf(fmaxf(v, -0.45f), 3.55f);
                const float sc = 4.0f / 255.0f;
                v = rintf((v + 0.45f) / sc) * sc - 0.45f;
            }
            xq[idx] = (_Float16)v;
        }
        {
            const float mn = qmn[0], sc = qsc[0];
            for (int idx = tid; idx < 64 * 224; idx += 256) {
                int q = idx / 224, p = idx - q * 224;
                float v = 0.0f;
                if (q < QDIM && p < PDIM) v = fquant(p1W[q * PDIM + p], mn, sc);
                pq[idx] = (_Float16)v;
            }
        }
        __syncthreads();
        f32x4 accp = {0.f, 0.f, 0.f, 0.f};
#pragma unroll
        for (int kc = 0; kc < 7; kc++) {
            half8 aF = *(const half8*)(pq + (w * 16 + l15) * 224 + kc * 32 + l4 * 8); // weights
            half8 bF = *(const half8*)(xq + l15 * 224 + kc * 32 + l4 * 8);            // xq^T
            accp = __builtin_amdgcn_mfma_f32_16x16x32_f16(aF, bF, accp, 0, 0, 0);
        }
#pragma unroll
        for (int j = 0; j < 4; j++) {
            int qj = w * 16 + l4 * 4 + j;
            accp[j] += (qj < QDIM) ? p1b[qj] : 0.0f;
        }
        *(f32x4*)(pix + l15 * 64 + w * 16 + l4 * 4) = accp;   // pix[batch][q]
        __syncthreads();
    }

    // ---------------- diagonal-pipelined scan: 54 phases, ONE barrier each ----------------
    const int aswz  = (l15 & 7) << 4;
    int boff[4];
#pragma unroll
    for (int kc = 0; kc < 4; kc++) boff[kc] = l15 * 256 + ((kc * 64 + l4 * 16) ^ aswz);
    const int cb0   = w * 64 + l4 * 8;                       // C-write col byte (nt=0)
    const int woff0 = l15 * 256 + (cb0 ^ aswz);
    const int woff1 = l15 * 256 + ((cb0 + 32) ^ aswz);
    const int h0off = hr * 256 + ((hc0 * 2) ^ ((hr & 7) << 4));
    const float* pixr = pix + hr * 64;

#define PHASE(P, SW, SR)                                                              \
    do {                                                                              \
        if ((P) < QDIM) {                                                             \
            float px = pixr[(P)];                                                     \
            half8 hh;                                                                 \
            _Pragma("unroll") for (int j = 0; j < 8; j++) {                           \
                float v = tanh_fast(fmaf(px, w0v[j], a0 * h0v[j]));                   \
                h0v[j] = v; hh[j] = (_Float16)v;                                      \
            }                                                                         \
            *(half8*)(actp + (SW) * 4096 + h0off) = hh;                               \
        }                                                                             \
        _Pragma("unroll") for (int i = 0; i < NDEEP; i++) {                           \
            int t_ = (P) - 1 - i;                                                     \
            if (t_ >= 0 && t_ < QDIM) {                                               \
                f32x4 acc0 = st[i][0] * adv[i];                                       \
                f32x4 acc1 = st[i][1] * adv[i];                                       \
                _Pragma("unroll") for (int kc = 0; kc < 4; kc++) {                    \
                    half8 b_ = *(const half8*)(actp + i * 8192 + (SR) * 4096 + boff[kc]); \
                    acc0 = __builtin_amdgcn_mfma_f32_16x16x32_f16(bw[i][0][kc], b_, acc0, 0, 0, 0); \
                    acc1 = __builtin_amdgcn_mfma_f32_16x16x32_f16(bw[i][1][kc], b_, acc1, 0, 0, 0); \
                }                                                                     \
                half4 hA, hB;                                                         \
                _Pragma("unroll") for (int j = 0; j < 4; j++) {                       \
                    acc0[j] = tanh_fast(acc0[j]);                                     \
                    acc1[j] = tanh_fast(acc1[j]);                                     \
                    hA[j] = (_Float16)acc0[j]; hB[j] = (_Float16)acc1[j];             \
                }                                                                     \
                st[i][0] = acc0; st[i][1] = acc1;                                     \
                if (i < NDEEP - 1) {                                                  \
                    *(half4*)(actp + (i + 1) * 8192 + (SW) * 4096 + woff0) = hA;      \
                    *(half4*)(actp + (i + 1) * 8192 + (SW) * 4096 + woff1) = hB;      \
                }                                                                     \
            }                                                                         \
        }                                                                             \
        __syncthreads();                                                              \
    } while (0)

#pragma unroll 1
    for (int p = 0; p < NPHASE; p += 2) {
        PHASE(p,     0, 1);
        PHASE(p + 1, 1, 0);
    }
#undef PHASE

    // ---------------- epilogue: out = relu(hs4 @ qweight(fc1)^T) @ fc2^T + fc2b ----------------
    float* hs4 = (float*)actp;                       // [16][136]
    *(f32x4*)(hs4 + l15 * 136 + w * 32 + l4 * 4)      = st[NDEEP - 1][0];
    *(f32x4*)(hs4 + l15 * 136 + w * 32 + 16 + l4 * 4) = st[NDEEP - 1][1];
    __syncthreads();

    float* tmp = pix;                                // [16][8]
    if (tid < 128) {
        int r = tid >> 3, jj = tid & 7;
        const float* hrow = hs4 + r * 136;
        const float* fw   = fc1W + jj * HDIM;
        const float mn = qmn[2], sc = qsc[2];
        float acc = 0.f;
#pragma unroll 4
        for (int p = 0; p < HDIM; p++) acc += hrow[p] * fquant(fw[p], mn, sc);
        tmp[r * 8 + jj] = fmaxf(acc, 0.f);
    }
    __syncthreads();
    if (tid < 160) {
        int r = tid / 10, o = tid - r * 10;
        float acc = fc2b[o];
#pragma unroll
        for (int jj = 0; jj < 8; jj++) acc += tmp[r * 8 + jj] * fc2W[o * 8 + jj];
        out[(size_t)(r0 + r) * 10 + o] = acc;
    }
}

extern "C" void kernel_launch(void* const* d_in, const int* in_sizes, int n_in,
                              void* d_out, int out_size, void* d_ws, size_t ws_size,
                              hipStream_t stream)
{
    const float* x    = (const float*)d_in[0];
    const float* cell = (const float*)d_in[1];
    const float* W0   = (const float*)d_in[2];
    const float* a0   = (const float*)d_in[3];
    const float* Wd   = (const float*)d_in[4];
    const float* ad   = (const float*)d_in[5];
    const float* p1W  = (const float*)d_in[6];
    const float* p1b  = (const float*)d_in[7];
    const float* fc1  = (const float*)d_in[8];
    const float* fc2W = (const float*)d_in[9];
    const float* fc2b = (const float*)d_in[10];

    dfr_all<<<512, 256, 0, stream>>>(x, cell, W0, a0, Wd, ad, p1W, p1b,
                                     fc1, fc2W, fc2b, (float*)d_out);
}

// Round 5
// 290.513 us; speedup vs baseline: 2.0173x; 1.2436x over previous
//
#include <hip/hip_runtime.h>
#include <hip/hip_fp16.h>

typedef __attribute__((ext_vector_type(8))) _Float16 half8;
typedef __attribute__((ext_vector_type(4))) _Float16 half4;
typedef __attribute__((ext_vector_type(4))) float f32x4;

#define B_TOT 8192
#define HDIM  128
#define NDEEP 5
#define PDIM  196
#define QDIM  49
#define BM    32
#define NPHASE (QDIM + NDEEP)   // 54, even

__device__ __forceinline__ float tanh_fast(float v) {
    // tanh(v) = 1 - 2/(exp(2v)+1); exp(2v) = exp2(v * 2*log2(e)). Saturates at +-inf.
    float e = __builtin_amdgcn_exp2f(v * 2.885390082f);
    float r = __builtin_amdgcn_rcpf(e + 1.0f);
    return fmaf(-2.0f, r, 1.0f);
}

__device__ __forceinline__ float fquant(float v, float mn, float sc) {
    // 8-bit uniform fake-quant: IEEE f32 div + rint (half-even) to match numpy
    return rintf((v - mn) / sc) * sc + mn;
}

// Fully fused DFR. grid=256 x 512 thr (8 waves), exactly 1 block/CU. Block owns 32
// batch rows. Wave w owns out-neuron cols [w*16, w*16+16); per layer it computes two
// 16-batch D tiles. Weights: bw[5][4] half8 = 80 VGPR/lane (fits the 256-reg cap an
// 8-wave block implies -> no spills, unlike round 4's 160-VGPR-per-wave layout).
// Diagonal pipeline: phase p runs h0(t=p) and deep layer i at t=p-1-i concurrently;
// one barrier per phase (54 total).
__global__ __launch_bounds__(512) void dfr_all(
    const float* __restrict__ x,    const float* __restrict__ cell_out,
    const float* __restrict__ W0,   const float* __restrict__ a0p,
    const float* __restrict__ Wd,   const float* __restrict__ adp,
    const float* __restrict__ p1W,  const float* __restrict__ p1b,
    const float* __restrict__ fc1W, const float* __restrict__ fc2W,
    const float* __restrict__ fc2b, float* __restrict__ out)
{
    __shared__ __align__(16) char smem[8192 + 10 * 8192];
    float* pix  = (float*)smem;          // [32 batch][64] f32 (q cols 0..48 valid)
    char*  actp = smem + 8192;           // act[producer 0..4][slot 0..1]: 32 rows x 256 B, swizzled

    const int tid  = threadIdx.x;
    const int lane = tid & 63;
    const int w    = tid >> 6;           // wave 0..7 (owns out-neuron cols w*16..w*16+15)
    const int l15  = lane & 15;
    const int l4   = lane >> 4;
    const int r0   = blockIdx.x * BM;

    float* sred = (float*)smem;          // reduce scratch (dead before pix written)

    // ---- per-tensor min/max (block-redundant, L2-resident) ----
    float qmn[8], qsc[8];                // 0:p1W 1:W0 2:fc1W 3..7:Wd[0..4]
    {
        const float* srcs[8] = { p1W, W0, fc1W, Wd, Wd + HDIM*HDIM, Wd + 2*HDIM*HDIM,
                                 Wd + 3*HDIM*HDIM, Wd + 4*HDIM*HDIM };
        const int    ns[8]   = { QDIM*PDIM, HDIM, 8*HDIM, HDIM*HDIM, HDIM*HDIM,
                                 HDIM*HDIM, HDIM*HDIM, HDIM*HDIM };
#pragma unroll
        for (int s = 0; s < 8; s++) {
            const float* p = srcs[s]; const int n = ns[s];
            float mn = 1e30f, mx = -1e30f;
            for (int i = tid; i < n; i += 512) { float v = p[i]; mn = fminf(mn, v); mx = fmaxf(mx, v); }
            for (int off = 32; off; off >>= 1) {
                mn = fminf(mn, __shfl_down(mn, off));
                mx = fmaxf(mx, __shfl_down(mx, off));
            }
            if (lane == 0) { sred[w] = mn; sred[8 + w] = mx; }
            __syncthreads();
            mn = fminf(fminf(fminf(sred[0], sred[1]), fminf(sred[2], sred[3])),
                       fminf(fminf(sred[4], sred[5]), fminf(sred[6], sred[7])));
            mx = fmaxf(fmaxf(fmaxf(sred[8], sred[9]), fmaxf(sred[10], sred[11])),
                       fmaxf(fmaxf(sred[12], sred[13]), fmaxf(sred[14], sred[15])));
            __syncthreads();
            qmn[s] = mn; qsc[s] = (mx - mn) / 255.0f;
        }
    }

    // ---- deep weights -> quantized f16 A-fragments in registers (16-col slice/wave) ----
    half8 bw[NDEEP][4];                  // [layer][kc] : 80 VGPR
#pragma unroll
    for (int i = 0; i < NDEEP; i++) {
        const float mn = qmn[3 + i], sc = qsc[3 + i];
#pragma unroll
        for (int kc = 0; kc < 4; kc++) {
            const float* src = Wd + (size_t)i * HDIM * HDIM
                             + (size_t)(w * 16 + l15) * HDIM + kc * 32 + l4 * 8;
            half8 h;
#pragma unroll
            for (int j = 0; j < 8; j++) h[j] = (_Float16)fquant(src[j], mn, sc);
            bw[i][kc] = h;
        }
    }

    const float a0 = a0p[0];
    float adv[NDEEP];
#pragma unroll
    for (int i = 0; i < NDEEP; i++) adv[i] = adp[i];

    // h0 elementwise: thread owns batch hr (0..31), 8 neurons hc0..hc0+7
    const int hr  = tid >> 4;
    const int hc0 = (tid & 15) * 8;
    float w0v[8], h0v[8];
#pragma unroll
    for (int j = 0; j < 8; j++) {
        w0v[j] = fquant(W0[hc0 + j], qmn[1], qsc[1]);
        h0v[j] = cell_out[(size_t)(r0 + hr) * HDIM + hc0 + j];
    }

    // deep state, D layout: col(batch)=bt*16+l15, row(neuron)=w*16 + l4*4+j
    f32x4 st[NDEEP][2];
#pragma unroll
    for (int i = 0; i < NDEEP; i++)
#pragma unroll
        for (int bt = 0; bt < 2; bt++)
            st[i][bt] = *(const f32x4*)(cell_out + (size_t)(1 + i) * B_TOT * HDIM
                                 + (size_t)(r0 + bt * 16 + l15) * HDIM + w * 16 + l4 * 4);

    // ---------------- phase 0: pix = quant(x) @ qweight(p1_W)^T + p1_b ----------------
    {
        _Float16* pq = (_Float16*)actp;            // [64][224]  (q rows, zero-padded)
        _Float16* xq = (_Float16*)(actp + 28672);  // [32][224]  (batch rows, zero-padded)
        for (int idx = tid; idx < 32 * 224; idx += 512) {
            int r = idx / 224, p = idx - r * 224;
            float v = 0.0f;
            if (p < PDIM) {
                v = x[(size_t)(r0 + r) * PDIM + p];
                v = fminf(fmaxf(v, -0.45f), 3.55f);
                const float sc = 4.0f / 255.0f;
                v = rintf((v + 0.45f) / sc) * sc - 0.45f;
            }
            xq[idx] = (_Float16)v;
        }
        {
            const float mn = qmn[0], sc = qsc[0];
            for (int idx = tid; idx < 64 * 224; idx += 512) {
                int q = idx / 224, p = idx - q * 224;
                float v = 0.0f;
                if (q < QDIM && p < PDIM) v = fquant(p1W[q * PDIM + p], mn, sc);
                pq[idx] = (_Float16)v;
            }
        }
        __syncthreads();
        const int qt = w & 3, bt = w >> 2;         // wave -> (q tile, batch tile)
        f32x4 accp = {0.f, 0.f, 0.f, 0.f};
#pragma unroll
        for (int kc = 0; kc < 7; kc++) {
            half8 aF = *(const half8*)(pq + (qt * 16 + l15) * 224 + kc * 32 + l4 * 8);
            half8 bF = *(const half8*)(xq + (bt * 16 + l15) * 224 + kc * 32 + l4 * 8);
            accp = __builtin_amdgcn_mfma_f32_16x16x32_f16(aF, bF, accp, 0, 0, 0);
        }
#pragma unroll
        for (int j = 0; j < 4; j++) {
            int qj = qt * 16 + l4 * 4 + j;
            accp[j] += (qj < QDIM) ? p1b[qj] : 0.0f;
        }
        *(f32x4*)(pix + (bt * 16 + l15) * 64 + qt * 16 + l4 * 4) = accp;  // pix[batch][q]
        __syncthreads();
    }

    // ---------------- diagonal-pipelined scan: 54 phases, ONE barrier each ----------------
    const int aswz = (l15 & 7) << 4;
    int boff[2][4];
#pragma unroll
    for (int bt = 0; bt < 2; bt++)
#pragma unroll
        for (int kc = 0; kc < 4; kc++)
            boff[bt][kc] = (bt * 16 + l15) * 256 + ((kc * 64 + l4 * 16) ^ aswz);
    const int cb = w * 32 + l4 * 8;                        // C-write col byte
    const int woff0 = l15 * 256 + (cb ^ aswz);             // bt=0
    const int woff1 = (16 + l15) * 256 + (cb ^ aswz);      // bt=1
    const int h0off = hr * 256 + ((hc0 * 2) ^ ((hr & 7) << 4));
    const float* pixr = pix + hr * 64;

#define PHASE(P, SW, SR)                                                              \
    do {                                                                              \
        if ((P) < QDIM) {                                                             \
            float px = pixr[(P)];                                                     \
            half8 hh;                                                                 \
            _Pragma("unroll") for (int j = 0; j < 8; j++) {                           \
                float v = tanh_fast(fmaf(px, w0v[j], a0 * h0v[j]));                   \
                h0v[j] = v; hh[j] = (_Float16)v;                                      \
            }                                                                         \
            *(half8*)(actp + (SW) * 8192 + h0off) = hh;                               \
        }                                                                             \
        _Pragma("unroll") for (int i = 0; i < NDEEP; i++) {                           \
            int t_ = (P) - 1 - i;                                                     \
            if (t_ >= 0 && t_ < QDIM) {                                               \
                f32x4 acc0 = st[i][0] * adv[i];                                       \
                f32x4 acc1 = st[i][1] * adv[i];                                       \
                const char* rbase = actp + i * 16384 + (SR) * 8192;                   \
                _Pragma("unroll") for (int kc = 0; kc < 4; kc++) {                    \
                    half8 b0 = *(const half8*)(rbase + boff[0][kc]);                  \
                    half8 b1 = *(const half8*)(rbase + boff[1][kc]);                  \
                    acc0 = __builtin_amdgcn_mfma_f32_16x16x32_f16(bw[i][kc], b0, acc0, 0, 0, 0); \
                    acc1 = __builtin_amdgcn_mfma_f32_16x16x32_f16(bw[i][kc], b1, acc1, 0, 0, 0); \
                }                                                                     \
                half4 hA, hB;                                                         \
                _Pragma("unroll") for (int j = 0; j < 4; j++) {                       \
                    acc0[j] = tanh_fast(acc0[j]);                                     \
                    acc1[j] = tanh_fast(acc1[j]);                                     \
                    hA[j] = (_Float16)acc0[j]; hB[j] = (_Float16)acc1[j];             \
                }                                                                     \
                st[i][0] = acc0; st[i][1] = acc1;                                     \
                if (i < NDEEP - 1) {                                                  \
                    char* wb = actp + (i + 1) * 16384 + (SW) * 8192;                  \
                    *(half4*)(wb + woff0) = hA;                                       \
                    *(half4*)(wb + woff1) = hB;                                       \
                }                                                                     \
            }                                                                         \
        }                                                                             \
        __syncthreads();                                                              \
    } while (0)

#pragma unroll 1
    for (int p = 0; p < NPHASE; p += 2) {
        PHASE(p,     0, 1);
        PHASE(p + 1, 1, 0);
    }
#undef PHASE

    // ---------------- epilogue: out = relu(hs4 @ qweight(fc1)^T) @ fc2^T + fc2b ----------------
    float* hs4 = (float*)actp;                       // [32][136]
    *(f32x4*)(hs4 + (l15)      * 136 + w * 16 + l4 * 4) = st[NDEEP - 1][0];
    *(f32x4*)(hs4 + (16 + l15) * 136 + w * 16 + l4 * 4) = st[NDEEP - 1][1];
    __syncthreads();

    float* tmp = pix;                                // [32][8]
    if (tid < 256) {
        int r = tid >> 3, jj = tid & 7;
        const float* hrow = hs4 + r * 136;
        const float* fw   = fc1W + jj * HDIM;
        const float mn = qmn[2], sc = qsc[2];
        float acc = 0.f;
#pragma unroll 4
        for (int p = 0; p < HDIM; p++) acc += hrow[p] * fquant(fw[p], mn, sc);
        tmp[r * 8 + jj] = fmaxf(acc, 0.f);
    }
    __syncthreads();
    if (tid < 320) {
        int r = tid / 10, o = tid - r * 10;
        float acc = fc2b[o];
#pragma unroll
        for (int jj = 0; jj < 8; jj++) acc += tmp[r * 8 + jj] * fc2W[o * 8 + jj];
        out[(size_t)(r0 + r) * 10 + o] = acc;
    }
}

extern "C" void kernel_launch(void* const* d_in, const int* in_sizes, int n_in,
                              void* d_out, int out_size, void* d_ws, size_t ws_size,
                              hipStream_t stream)
{
    const float* x    = (const float*)d_in[0];
    const float* cell = (const float*)d_in[1];
    const float* W0   = (const float*)d_in[2];
    const float* a0   = (const float*)d_in[3];
    const float* Wd   = (const float*)d_in[4];
    const float* ad   = (const float*)d_in[5];
    const float* p1W  = (const float*)d_in[6];
    const float* p1b  = (const float*)d_in[7];
    const float* fc1  = (const float*)d_in[8];
    const float* fc2W = (const float*)d_in[9];
    const float* fc2b = (const float*)d_in[10];

    dfr_all<<<256, 512, 0, stream>>>(x, cell, W0, a0, Wd, ad, p1W, p1b,
                                     fc1, fc2W, fc2b, (float*)d_out);
}